// Round 2
// baseline (627.466 us; speedup 1.0000x reference)
//
#include <hip/hip_runtime.h>
#include <math.h>

// Problem constants (from reference)
static constexpr int Zc  = 64;    // z_dim
static constexpr int Xc  = 32;    // x_dim
static constexpr int THc = 128;   // trans_hidden
static constexpr int OHc = 64;    // obs_hidden
static constexpr int Bc  = 4096;  // batch
static constexpr int Tc  = 256;   // time

__device__ __forceinline__ float sigf(float x) {
  float e = __expf(-x);
  return __builtin_amdgcn_rcpf(1.0f + e);
}
__device__ __forceinline__ float tanh_fast(float x) {
  float xc = fminf(fmaxf(x, -15.0f), 15.0f);
  float e  = __expf(-2.0f * xc);
  return (1.0f - e) * __builtin_amdgcn_rcpf(1.0f + e);
}

// dot of 32 register weights (constant offset into wbig) with 32 LDS floats
template <int OFF>
__device__ __forceinline__ float dot32(const float (&w)[160], const float* x) {
  float a0 = 0.f, a1 = 0.f, a2 = 0.f, a3 = 0.f;
#pragma unroll
  for (int k = 0; k < 8; ++k) {
    float4 v = ((const float4*)x)[k];
    a0 = fmaf(w[OFF + 4 * k + 0], v.x, a0);
    a1 = fmaf(w[OFF + 4 * k + 1], v.y, a1);
    a2 = fmaf(w[OFF + 4 * k + 2], v.z, a2);
    a3 = fmaf(w[OFF + 4 * k + 3], v.w, a3);
  }
  return (a0 + a1) + (a2 + a3);
}

template <int OFF>
__device__ __forceinline__ float dot64(const float (&w)[160], const float* x) {
  float a0 = 0.f, a1 = 0.f, a2 = 0.f, a3 = 0.f;
#pragma unroll
  for (int k = 0; k < 16; ++k) {
    float4 v = ((const float4*)x)[k];
    a0 = fmaf(w[OFF + 4 * k + 0], v.x, a0);
    a1 = fmaf(w[OFF + 4 * k + 1], v.y, a1);
    a2 = fmaf(w[OFF + 4 * k + 2], v.z, a2);
    a3 = fmaf(w[OFF + 4 * k + 3], v.w, a3);
  }
  return (a0 + a1) + (a2 + a3);
}

template <int OFF>
__device__ __forceinline__ void load32(float (&w)[160], const float* src) {
#pragma unroll
  for (int k = 0; k < 8; ++k) {
    float4 v = ((const float4*)src)[k];
    w[OFF + 4 * k + 0] = v.x; w[OFF + 4 * k + 1] = v.y;
    w[OFF + 4 * k + 2] = v.z; w[OFF + 4 * k + 3] = v.w;
  }
}
template <int OFF>
__device__ __forceinline__ void load64(float (&w)[160], const float* src) {
  load32<OFF>(w, src);
  load32<OFF + 32>(w, src + 32);
}

// Serial recurrence, 1 block x 512 threads (8 waves), 3 barriers per step.
//   P1: rnn_out (fused GRU matvec+elementwise, waves 0-3, shfl-reduced)
//       || obs hidden for step t-1 (waves 4-5)
//   P2: trans hiddens + z_lin (waves 0-4) || obs final -> out[t-1] (wave 5)
//   P3: gate+pm+z combine in-lane (waves 6-7)
// Weights live in per-thread registers (wbig[160] overlay, template offsets).
__global__ __launch_bounds__(512) void chain_kernel(
    const float* __restrict__ z0, const float* __restrict__ h0,
    const float* __restrict__ W_ih, const float* __restrict__ W_hh,
    const float* __restrict__ b_ih, const float* __restrict__ b_hh,
    const float* __restrict__ W_gzh, const float* __restrict__ b_gzh,
    const float* __restrict__ W_ghz, const float* __restrict__ b_ghz,
    const float* __restrict__ W_pzh, const float* __restrict__ b_pzh,
    const float* __restrict__ W_phz, const float* __restrict__ b_phz,
    const float* __restrict__ W_zloc, const float* __restrict__ b_zloc,
    const float* __restrict__ W_olh, const float* __restrict__ b_olh,
    const float* __restrict__ W_olx, const float* __restrict__ b_olx,
    const float* __restrict__ W_osh, const float* __restrict__ b_osh,
    const float* __restrict__ W_osx, const float* __restrict__ b_osx,
    float* __restrict__ out) {
  const int tid  = threadIdx.x;
  const int lane = tid & 63;
  const int wv   = tid >> 6;

  __shared__ __align__(16) float zbuf[64];
  __shared__ __align__(16) float hA[64];
  __shared__ __align__(16) float hB[64];
  __shared__ __align__(16) float abuf[128];
  __shared__ __align__(16) float cbuf[128];
  __shared__ __align__(16) float zlinbuf[64];
  __shared__ __align__(16) float olbuf[64];
  __shared__ __align__(16) float osbuf[64];

  float wbig[160];
  float bA = 0.f, bB = 0.f, bC = 0.f, bD = 0.f, b2 = 0.f;

  // ---------------- weight staging into registers ----------------
  if (tid < 256) {
    // waves 0-3: GRU. j = output index, q = quarter-chunk of concat [z|h].
    const int j = (wv << 4) + (lane & 15);
    const int q = lane >> 4;
    const float* Wz = (q < 2) ? W_ih : W_hh;
    const int coff = (q & 1) * 32;
    load32<0 >(wbig, Wz + (j) * 64 + coff);        // r row chunk
    load32<32>(wbig, Wz + (64 + j) * 64 + coff);   // u row chunk
    load32<64>(wbig, Wz + (128 + j) * 64 + coff);  // n row chunk (i_n / h_n part)
    bA = b_ih[j] + b_hh[j];
    bB = b_ih[64 + j] + b_hh[64 + j];
    bC = b_ih[128 + j];
    bD = b_hh[128 + j];
    if (tid < 128) { load64<96>(wbig, W_gzh + tid * 64);         b2 = b_gzh[tid]; }
    else           { load64<96>(wbig, W_pzh + (tid - 128) * 64); b2 = b_pzh[tid - 128]; }
  } else if (tid < 320) {
    // wave 4: obs-loc hidden row + zloc row
    const int r = tid - 256;
    load64<0 >(wbig, W_olh + r * 64);  bA = b_olh[r];
    load64<96>(wbig, W_zloc + r * 64); b2 = b_zloc[r];
  } else if (tid < 384) {
    // wave 5: obs-scale hidden row + obs final row
    const int r = tid - 320;
    load64<0>(wbig, W_osh + r * 64);   bA = b_osh[r];
    if (tid < 352) { load64<96>(wbig, W_olx + r * 64);          b2 = b_olx[r]; }
    else           { load64<96>(wbig, W_osx + (tid - 352) * 64); b2 = b_osx[tid - 352]; }
  } else {
    // waves 6-7: gate + pm half-rows. j = row, half = K-half of TH=128.
    const int j    = ((wv & 1) << 5) + (lane & 31);
    const int half = lane >> 5;
    load64<0 >(wbig, W_ghz + j * 128 + half * 64); bA = b_ghz[j];
    load64<64>(wbig, W_phz + j * 128 + half * 64); bB = b_phz[j];
  }

  if (tid < 64) { zbuf[tid] = z0[tid]; hA[tid] = h0[tid]; }
  __syncthreads();

  for (int t = 0; t <= Tc; ++t) {
    const bool step = (t < Tc);
    const bool obs  = (t >= 1);
    float* hold = (t & 1) ? hB : hA;
    float* hnew = (t & 1) ? hA : hB;

    // ---- P1: rnn_out (fused GRU) || obs hidden (t-1) ----
    if (step && tid < 256) {
      const int j = (wv << 4) + (lane & 15);
      const int q = lane >> 4;
      const float* x = ((q < 2) ? zbuf : hold) + (q & 1) * 32;
      float pr = dot32<0 >(wbig, x);
      float pu = dot32<32>(wbig, x);
      float pn = dot32<64>(wbig, x);
      pr += __shfl_xor(pr, 16, 64); pr += __shfl_xor(pr, 32, 64);
      pu += __shfl_xor(pu, 16, 64); pu += __shfl_xor(pu, 32, 64);
      pn += __shfl_xor(pn, 16, 64);
      float pno = __shfl_xor(pn, 32, 64);
      float i_n = ((lane < 32) ? pn : pno) + bC;
      float h_n = ((lane < 32) ? pno : pn) + bD;
      float r  = sigf(pr + bA);
      float u  = sigf(pu + bB);
      float nn = tanh_fast(i_n + r * h_n);
      float hv = (1.f - u) * nn + u * hold[j];
      if (lane < 16) hnew[j] = hv;
    }
    if (obs && tid >= 256 && tid < 384) {
      const int r = (tid < 320) ? (tid - 256) : (tid - 320);
      float acc = dot64<0>(wbig, zbuf) + bA;   // zbuf holds Z_t (for out[t-1])
      acc = fmaxf(acc, 0.f);
      if (tid < 320) olbuf[r] = acc; else osbuf[r] = acc;
    }
    __syncthreads();

    // ---- P2: trans hiddens + z_lin || obs final -> out[t-1] ----
    if (step && tid < 320) {
      float acc = dot64<96>(wbig, hnew) + b2;
      if (tid < 128)      abuf[tid] = fmaxf(acc, 0.f);
      else if (tid < 256) cbuf[tid - 128] = fmaxf(acc, 0.f);
      else                zlinbuf[tid - 256] = acc;
    }
    if (obs && tid >= 320 && tid < 384) {
      const float* x = (tid < 352) ? olbuf : osbuf;
      float acc = dot64<96>(wbig, x) + b2;
      out[(size_t)(t - 1) * 64 + (tid - 320)] = fmaxf(acc, 0.f);
    }
    __syncthreads();

    // ---- P3: gate + pm + z combine (waves 6-7, in-lane) ----
    if (step && tid >= 384) {
      const int j    = ((wv & 1) << 5) + (lane & 31);
      const int half = lane >> 5;
      float sg = dot64<0 >(wbig, abuf + half * 64);
      float sp = dot64<64>(wbig, cbuf + half * 64);
      sg += __shfl_xor(sg, 32, 64);
      sp += __shfl_xor(sp, 32, 64);
      float zl = zlinbuf[j];
      float g  = sigf(sg + bA);
      float zv = (1.f - g) * zl + g * (sp + bB);
      if (lane < 32) zbuf[j] = zv;
    }
    __syncthreads();
  }
}

// out[n] = out[n mod 16384] for n >= 16384; 16384 = T*2X is a power of two.
__global__ __launch_bounds__(256) void bcast_kernel(float* __restrict__ out) {
  const size_t total4 = (size_t)Bc * Tc * (2 * Xc) / 4;  // 16,777,216 float4
  const size_t src4   = (size_t)Tc * (2 * Xc) / 4;        // 4096 float4
  const float4* s = (const float4*)out;
  float4* o = (float4*)out;
  size_t stride = (size_t)gridDim.x * blockDim.x;
  for (size_t i = (size_t)blockIdx.x * blockDim.x + threadIdx.x + src4;
       i < total4; i += stride) {
    o[i] = s[i & (src4 - 1)];
  }
}

extern "C" void kernel_launch(void* const* d_in, const int* in_sizes, int n_in,
                              void* d_out, int out_size, void* d_ws, size_t ws_size,
                              hipStream_t stream) {
  (void)in_sizes; (void)n_in; (void)d_ws; (void)ws_size; (void)out_size;
  const float* z0     = (const float*)d_in[1];
  const float* h0     = (const float*)d_in[2];
  const float* W_ih   = (const float*)d_in[3];
  const float* W_hh   = (const float*)d_in[4];
  const float* b_ih   = (const float*)d_in[5];
  const float* b_hh   = (const float*)d_in[6];
  const float* W_gzh  = (const float*)d_in[7];
  const float* b_gzh  = (const float*)d_in[8];
  const float* W_ghz  = (const float*)d_in[9];
  const float* b_ghz  = (const float*)d_in[10];
  const float* W_pzh  = (const float*)d_in[11];
  const float* b_pzh  = (const float*)d_in[12];
  const float* W_phz  = (const float*)d_in[13];
  const float* b_phz  = (const float*)d_in[14];
  const float* W_zloc = (const float*)d_in[15];
  const float* b_zloc = (const float*)d_in[16];
  const float* W_olh  = (const float*)d_in[19];
  const float* b_olh  = (const float*)d_in[20];
  const float* W_olx  = (const float*)d_in[21];
  const float* b_olx  = (const float*)d_in[22];
  const float* W_osh  = (const float*)d_in[23];
  const float* b_osh  = (const float*)d_in[24];
  const float* W_osx  = (const float*)d_in[25];
  const float* b_osx  = (const float*)d_in[26];
  float* out = (float*)d_out;

  chain_kernel<<<1, 512, 0, stream>>>(
      z0, h0, W_ih, W_hh, b_ih, b_hh,
      W_gzh, b_gzh, W_ghz, b_ghz, W_pzh, b_pzh, W_phz, b_phz,
      W_zloc, b_zloc, W_olh, b_olh, W_olx, b_olx,
      W_osh, b_osh, W_osx, b_osx, out);

  bcast_kernel<<<2048, 256, 0, stream>>>(out);
}

// Round 3
// 627.335 us; speedup vs baseline: 1.0002x; 1.0002x over previous
//
#include <hip/hip_runtime.h>
#include <math.h>

// Problem constants (from reference)
static constexpr int Zc  = 64;    // z_dim
static constexpr int Xc  = 32;    // x_dim
static constexpr int THc = 128;   // trans_hidden
static constexpr int OHc = 64;    // obs_hidden
static constexpr int Bc  = 4096;  // batch
static constexpr int Tc  = 256;   // time

__device__ __forceinline__ float sigf(float x) {
  float e = __expf(-x);
  return __builtin_amdgcn_rcpf(1.0f + e);
}
__device__ __forceinline__ float tanh_fast(float x) {
  float xc = fminf(fmaxf(x, -15.0f), 15.0f);
  float e  = __expf(-2.0f * xc);
  return (1.0f - e) * __builtin_amdgcn_rcpf(1.0f + e);
}

// dot of 32 register weights (constant offset into wbig) with 32 LDS floats
template <int OFF>
__device__ __forceinline__ float dot32(const float (&w)[160], const float* x) {
  float a0 = 0.f, a1 = 0.f, a2 = 0.f, a3 = 0.f;
#pragma unroll
  for (int k = 0; k < 8; ++k) {
    float4 v = ((const float4*)x)[k];
    a0 = fmaf(w[OFF + 4 * k + 0], v.x, a0);
    a1 = fmaf(w[OFF + 4 * k + 1], v.y, a1);
    a2 = fmaf(w[OFF + 4 * k + 2], v.z, a2);
    a3 = fmaf(w[OFF + 4 * k + 3], v.w, a3);
  }
  return (a0 + a1) + (a2 + a3);
}

template <int OFF>
__device__ __forceinline__ float dot64(const float (&w)[160], const float* x) {
  float a0 = 0.f, a1 = 0.f, a2 = 0.f, a3 = 0.f;
#pragma unroll
  for (int k = 0; k < 16; ++k) {
    float4 v = ((const float4*)x)[k];
    a0 = fmaf(w[OFF + 4 * k + 0], v.x, a0);
    a1 = fmaf(w[OFF + 4 * k + 1], v.y, a1);
    a2 = fmaf(w[OFF + 4 * k + 2], v.z, a2);
    a3 = fmaf(w[OFF + 4 * k + 3], v.w, a3);
  }
  return (a0 + a1) + (a2 + a3);
}

template <int OFF>
__device__ __forceinline__ void load32(float (&w)[160], const float* src) {
#pragma unroll
  for (int k = 0; k < 8; ++k) {
    float4 v = ((const float4*)src)[k];
    w[OFF + 4 * k + 0] = v.x; w[OFF + 4 * k + 1] = v.y;
    w[OFF + 4 * k + 2] = v.z; w[OFF + 4 * k + 3] = v.w;
  }
}
template <int OFF>
__device__ __forceinline__ void load64(float (&w)[160], const float* src) {
  load32<OFF>(w, src);
  load32<OFF + 32>(w, src + 32);
}

// Serial recurrence, 1 block x 512 threads (8 waves), 3 barriers per step.
//   P1: rnn_out (fused GRU matvec+elementwise, waves 0-3, shfl-reduced)
//       || obs hidden for step t-1 (waves 4-5)
//   P2: trans hiddens + z_lin (waves 0-4) || obs final -> out[t-1] (wave 5)
//   P3: gate+pm+z combine in-lane (waves 6-7)
// Weights live in per-thread registers (wbig[160] overlay, template offsets).
// __launch_bounds__(512, 2): 2 waves/EU min -> 256-VGPR budget, no scratch spill.
__global__ __launch_bounds__(512, 2) void chain_kernel(
    const float* __restrict__ z0, const float* __restrict__ h0,
    const float* __restrict__ W_ih, const float* __restrict__ W_hh,
    const float* __restrict__ b_ih, const float* __restrict__ b_hh,
    const float* __restrict__ W_gzh, const float* __restrict__ b_gzh,
    const float* __restrict__ W_ghz, const float* __restrict__ b_ghz,
    const float* __restrict__ W_pzh, const float* __restrict__ b_pzh,
    const float* __restrict__ W_phz, const float* __restrict__ b_phz,
    const float* __restrict__ W_zloc, const float* __restrict__ b_zloc,
    const float* __restrict__ W_olh, const float* __restrict__ b_olh,
    const float* __restrict__ W_olx, const float* __restrict__ b_olx,
    const float* __restrict__ W_osh, const float* __restrict__ b_osh,
    const float* __restrict__ W_osx, const float* __restrict__ b_osx,
    float* __restrict__ out) {
  const int tid  = threadIdx.x;
  const int lane = tid & 63;
  const int wv   = tid >> 6;

  __shared__ __align__(16) float zbuf[64];
  __shared__ __align__(16) float hA[64];
  __shared__ __align__(16) float hB[64];
  __shared__ __align__(16) float abuf[128];
  __shared__ __align__(16) float cbuf[128];
  __shared__ __align__(16) float zlinbuf[64];
  __shared__ __align__(16) float olbuf[64];
  __shared__ __align__(16) float osbuf[64];

  float wbig[160];
  float bA = 0.f, bB = 0.f, bC = 0.f, bD = 0.f, b2 = 0.f;

  // ---------------- weight staging into registers ----------------
  if (tid < 256) {
    // waves 0-3: GRU. j = output index, q = quarter-chunk of concat [z|h].
    const int j = (wv << 4) + (lane & 15);
    const int q = lane >> 4;
    const float* Wz = (q < 2) ? W_ih : W_hh;
    const int coff = (q & 1) * 32;
    load32<0 >(wbig, Wz + (j) * 64 + coff);        // r row chunk
    load32<32>(wbig, Wz + (64 + j) * 64 + coff);   // u row chunk
    load32<64>(wbig, Wz + (128 + j) * 64 + coff);  // n row chunk (i_n / h_n part)
    bA = b_ih[j] + b_hh[j];
    bB = b_ih[64 + j] + b_hh[64 + j];
    bC = b_ih[128 + j];
    bD = b_hh[128 + j];
    if (tid < 128) { load64<96>(wbig, W_gzh + tid * 64);         b2 = b_gzh[tid]; }
    else           { load64<96>(wbig, W_pzh + (tid - 128) * 64); b2 = b_pzh[tid - 128]; }
  } else if (tid < 320) {
    // wave 4: obs-loc hidden row + zloc row
    const int r = tid - 256;
    load64<0 >(wbig, W_olh + r * 64);  bA = b_olh[r];
    load64<96>(wbig, W_zloc + r * 64); b2 = b_zloc[r];
  } else if (tid < 384) {
    // wave 5: obs-scale hidden row + obs final row
    const int r = tid - 320;
    load64<0>(wbig, W_osh + r * 64);   bA = b_osh[r];
    if (tid < 352) { load64<96>(wbig, W_olx + r * 64);          b2 = b_olx[r]; }
    else           { load64<96>(wbig, W_osx + (tid - 352) * 64); b2 = b_osx[tid - 352]; }
  } else {
    // waves 6-7: gate + pm half-rows. j = row, half = K-half of TH=128.
    const int j    = ((wv & 1) << 5) + (lane & 31);
    const int half = lane >> 5;
    load64<0 >(wbig, W_ghz + j * 128 + half * 64); bA = b_ghz[j];
    load64<64>(wbig, W_phz + j * 128 + half * 64); bB = b_phz[j];
  }

  if (tid < 64) { zbuf[tid] = z0[tid]; hA[tid] = h0[tid]; }
  __syncthreads();

  for (int t = 0; t <= Tc; ++t) {
    const bool step = (t < Tc);
    const bool obs  = (t >= 1);
    float* hold = (t & 1) ? hB : hA;
    float* hnew = (t & 1) ? hA : hB;

    // ---- P1: rnn_out (fused GRU) || obs hidden (t-1) ----
    if (step && tid < 256) {
      const int j = (wv << 4) + (lane & 15);
      const int q = lane >> 4;
      const float* x = ((q < 2) ? zbuf : hold) + (q & 1) * 32;
      float pr = dot32<0 >(wbig, x);
      float pu = dot32<32>(wbig, x);
      float pn = dot32<64>(wbig, x);
      pr += __shfl_xor(pr, 16, 64); pr += __shfl_xor(pr, 32, 64);
      pu += __shfl_xor(pu, 16, 64); pu += __shfl_xor(pu, 32, 64);
      pn += __shfl_xor(pn, 16, 64);
      float pno = __shfl_xor(pn, 32, 64);
      float i_n = ((lane < 32) ? pn : pno) + bC;
      float h_n = ((lane < 32) ? pno : pn) + bD;
      float r  = sigf(pr + bA);
      float u  = sigf(pu + bB);
      float nn = tanh_fast(i_n + r * h_n);
      float hv = (1.f - u) * nn + u * hold[j];
      if (lane < 16) hnew[j] = hv;
    }
    if (obs && tid >= 256 && tid < 384) {
      const int r = (tid < 320) ? (tid - 256) : (tid - 320);
      float acc = dot64<0>(wbig, zbuf) + bA;   // zbuf holds Z_t (for out[t-1])
      acc = fmaxf(acc, 0.f);
      if (tid < 320) olbuf[r] = acc; else osbuf[r] = acc;
    }
    __syncthreads();

    // ---- P2: trans hiddens + z_lin || obs final -> out[t-1] ----
    if (step && tid < 320) {
      float acc = dot64<96>(wbig, hnew) + b2;
      if (tid < 128)      abuf[tid] = fmaxf(acc, 0.f);
      else if (tid < 256) cbuf[tid - 128] = fmaxf(acc, 0.f);
      else                zlinbuf[tid - 256] = acc;
    }
    if (obs && tid >= 320 && tid < 384) {
      const float* x = (tid < 352) ? olbuf : osbuf;
      float acc = dot64<96>(wbig, x) + b2;
      out[(size_t)(t - 1) * 64 + (tid - 320)] = fmaxf(acc, 0.f);
    }
    __syncthreads();

    // ---- P3: gate + pm + z combine (waves 6-7, in-lane) ----
    if (step && tid >= 384) {
      const int j    = ((wv & 1) << 5) + (lane & 31);
      const int half = lane >> 5;
      float sg = dot64<0 >(wbig, abuf + half * 64);
      float sp = dot64<64>(wbig, cbuf + half * 64);
      sg += __shfl_xor(sg, 32, 64);
      sp += __shfl_xor(sp, 32, 64);
      float zl = zlinbuf[j];
      float g  = sigf(sg + bA);
      float zv = (1.f - g) * zl + g * (sp + bB);
      if (lane < 32) zbuf[j] = zv;
    }
    __syncthreads();
  }
}

// out[n] = out[n mod 16384] for n >= 16384; 16384 = T*2X is a power of two.
__global__ __launch_bounds__(256) void bcast_kernel(float* __restrict__ out) {
  const size_t total4 = (size_t)Bc * Tc * (2 * Xc) / 4;  // 16,777,216 float4
  const size_t src4   = (size_t)Tc * (2 * Xc) / 4;        // 4096 float4
  const float4* s = (const float4*)out;
  float4* o = (float4*)out;
  size_t stride = (size_t)gridDim.x * blockDim.x;
  for (size_t i = (size_t)blockIdx.x * blockDim.x + threadIdx.x + src4;
       i < total4; i += stride) {
    o[i] = s[i & (src4 - 1)];
  }
}

extern "C" void kernel_launch(void* const* d_in, const int* in_sizes, int n_in,
                              void* d_out, int out_size, void* d_ws, size_t ws_size,
                              hipStream_t stream) {
  (void)in_sizes; (void)n_in; (void)d_ws; (void)ws_size; (void)out_size;
  const float* z0     = (const float*)d_in[1];
  const float* h0     = (const float*)d_in[2];
  const float* W_ih   = (const float*)d_in[3];
  const float* W_hh   = (const float*)d_in[4];
  const float* b_ih   = (const float*)d_in[5];
  const float* b_hh   = (const float*)d_in[6];
  const float* W_gzh  = (const float*)d_in[7];
  const float* b_gzh  = (const float*)d_in[8];
  const float* W_ghz  = (const float*)d_in[9];
  const float* b_ghz  = (const float*)d_in[10];
  const float* W_pzh  = (const float*)d_in[11];
  const float* b_pzh  = (const float*)d_in[12];
  const float* W_phz  = (const float*)d_in[13];
  const float* b_phz  = (const float*)d_in[14];
  const float* W_zloc = (const float*)d_in[15];
  const float* b_zloc = (const float*)d_in[16];
  const float* W_olh  = (const float*)d_in[19];
  const float* b_olh  = (const float*)d_in[20];
  const float* W_olx  = (const float*)d_in[21];
  const float* b_olx  = (const float*)d_in[22];
  const float* W_osh  = (const float*)d_in[23];
  const float* b_osh  = (const float*)d_in[24];
  const float* W_osx  = (const float*)d_in[25];
  const float* b_osx  = (const float*)d_in[26];
  float* out = (float*)d_out;

  chain_kernel<<<1, 512, 0, stream>>>(
      z0, h0, W_ih, W_hh, b_ih, b_hh,
      W_gzh, b_gzh, W_ghz, b_ghz, W_pzh, b_pzh, W_phz, b_phz,
      W_zloc, b_zloc, W_olh, b_olh, W_olx, b_olx,
      W_osh, b_osh, W_osx, b_osx, out);

  bcast_kernel<<<2048, 256, 0, stream>>>(out);
}